// Round 6
// baseline (166.830 us; speedup 1.0000x reference)
//
#include <hip/hip_runtime.h>

#define B_ 16
#define C_ 12
#define H_ 384
#define W_ 384
#define LK 96
#define HW_ (H_ * W_)            // 147456
#define CHW (C_ * HW_)           // 1769472
#define LK2 (LK * LK)            // 9216
#define TPB 256
#define NGRP (B_ * H_ * (W_ / 4))   // 589824 4-pixel groups, 1 per thread
#define NBLK (NGRP / TPB)           // 2304 blocks
#define NTOT ((double)(B_ * C_ * H_ * W_))

__device__ __forceinline__ float mask_w(float v) {
    // Sequential threshold masking collapses to 3 compares (verified absmax=0).
    const float T2 = (133.0f - 33.44f) / 47.54f;
    const float T3 = (181.0f - 33.44f) / 47.54f;
    const float T4 = (255.0f - 33.44f) / 47.54f;
    return v < T2 ? 5.0f : (v < T3 ? 10.0f : (v < T4 ? 30.0f : v));
}

// One channel-step of the fused loss for one 4-pixel group.
__device__ __forceinline__ void step(
    const float4& vt, const float4& vp, const float4& xv, float fh,
    const float* tap, float4& s, float4& t, float& acc)
{
    const float e0 = tap[0] + fh * (tap[3] - tap[0]);
    const float e1 = tap[1] + fh * (tap[4] - tap[1]);
    const float e2 = tap[2] + fh * (tap[5] - tap[2]);
    acc += (mask_w(vt.x) + s.x + t.x) * fabsf(vp.x - vt.x);
    s.x += fabsf(vt.x - xv.x); t.x += 0.375f * e0 + 0.625f * e1;
    acc += (mask_w(vt.y) + s.y + t.y) * fabsf(vp.y - vt.y);
    s.y += fabsf(vt.y - xv.y); t.y += 0.125f * e0 + 0.875f * e1;
    acc += (mask_w(vt.z) + s.z + t.z) * fabsf(vp.z - vt.z);
    s.z += fabsf(vt.z - xv.z); t.z += 0.875f * e1 + 0.125f * e2;
    acc += (mask_w(vt.w) + s.w + t.w) * fabsf(vp.w - vt.w);
    s.w += fabsf(vt.w - xv.w); t.w += 0.625f * e1 + 0.375f * e2;
}

__global__ __launch_bounds__(TPB) void loss_main(
    const float* __restrict__ y_pre, const float* __restrict__ y_true,
    const float* __restrict__ x_l, const float* __restrict__ wlk,
    double* __restrict__ partial, unsigned* __restrict__ cnt,
    float* __restrict__ out)
{
    const int g = blockIdx.x * TPB + threadIdx.x;
    const int j = g % (W_ / 4);
    const int t = g / (W_ / 4);
    const int h = t % H_;
    const int b = t / H_;

    // bilinear geometry (half-pixel, scale 4, clamped == jax renorm)
    const float src_h = h * 0.25f - 0.375f;
    const float kf = floorf(src_h);
    const float fh = src_h - kf;
    const int k0 = max((int)kf, 0);
    const int k1 = min((int)kf + 1, LK - 1);
    const int jm1 = max(j - 1, 0), jp1 = min(j + 1, LK - 1);
    const int rm0 = k0 * LK + jm1, rc0 = k0 * LK + j, rp0 = k0 * LK + jp1;
    const int rm1 = k1 * LK + jm1, rc1 = k1 * LK + j, rp1 = k1 * LK + jp1;

    const int pix = h * W_ + j * 4;
    const float4 xv = *(const float4*)(x_l + b * HW_ + pix);

    const float* yt = y_true + (size_t)b * CHW + pix;
    const float* yp = y_pre  + (size_t)b * CHW + pix;
    const float* L  = wlk + (size_t)b * C_ * LK2;

    float4 s4 = {0,0,0,0}, t4 = {0,0,0,0};
    float acc = 0.f;

    // software pipeline: y-streams 3 channels ahead, taps 2 ahead.
    // All stage indices are compile-time constants after full unroll.
    float4 vt[4], vp[4];
    float tap[3][6];

    #pragma unroll
    for (int c = 0; c < 3; ++c) {            // prologue: y channels 0..2
        vt[c] = *(const float4*)(yt + c * HW_);
        vp[c] = *(const float4*)(yp + c * HW_);
    }
    #pragma unroll
    for (int c = 0; c < 2; ++c) {            // prologue: taps channels 0..1
        const int lo = c * LK2;
        tap[c][0] = L[lo + rm0]; tap[c][1] = L[lo + rc0]; tap[c][2] = L[lo + rp0];
        tap[c][3] = L[lo + rm1]; tap[c][4] = L[lo + rc1]; tap[c][5] = L[lo + rp1];
    }

    #pragma unroll
    for (int c = 0; c < C_; ++c) {
        if (c + 3 < C_) {                    // prefetch y channel c+3
            vt[(c + 3) & 3] = *(const float4*)(yt + (c + 3) * HW_);
            vp[(c + 3) & 3] = *(const float4*)(yp + (c + 3) * HW_);
        }
        if (c + 2 < C_) {                    // prefetch taps channel c+2
            const int lo = (c + 2) * LK2;
            float* tp = tap[(c + 2) % 3];
            tp[0] = L[lo + rm0]; tp[1] = L[lo + rc0]; tp[2] = L[lo + rp0];
            tp[3] = L[lo + rm1]; tp[4] = L[lo + rc1]; tp[5] = L[lo + rp1];
        }
        step(vt[c & 3], vp[c & 3], xv, fh, tap[c % 3], s4, t4, acc);
    }

    // --- block reduction (double) ---
    double v = (double)acc;
    #pragma unroll
    for (int off = 32; off > 0; off >>= 1) v += __shfl_down(v, off, 64);
    __shared__ double lds[TPB / 64];
    __shared__ int is_last;
    const int lane = threadIdx.x & 63, wid = threadIdx.x >> 6;
    if (lane == 0) lds[wid] = v;
    __syncthreads();
    if (threadIdx.x == 0) {
        const double bsum = lds[0] + lds[1] + lds[2] + lds[3];
        __hip_atomic_store(&partial[blockIdx.x], bsum, __ATOMIC_RELAXED,
                           __HIP_MEMORY_SCOPE_AGENT);
        __threadfence();                                   // release
        const unsigned ticket =
            __hip_atomic_fetch_add(cnt, 1u, __ATOMIC_ACQ_REL, __HIP_MEMORY_SCOPE_AGENT);
        is_last = (ticket == NBLK - 1);
    }
    __syncthreads();
    if (!is_last) return;

    // --- last block finalizes (fixed order -> deterministic) ---
    __threadfence();                                       // acquire
    double f = 0.0;
    for (int i = threadIdx.x; i < NBLK; i += TPB)
        f += __hip_atomic_load(&partial[i], __ATOMIC_RELAXED, __HIP_MEMORY_SCOPE_AGENT);
    #pragma unroll
    for (int off = 32; off > 0; off >>= 1) f += __shfl_down(f, off, 64);
    __syncthreads();
    if (lane == 0) lds[wid] = f;
    __syncthreads();
    if (threadIdx.x == 0)
        out[0] = (float)((lds[0] + lds[1] + lds[2] + lds[3]) / NTOT);
}

extern "C" void kernel_launch(void* const* d_in, const int* in_sizes, int n_in,
                              void* d_out, int out_size, void* d_ws, size_t ws_size,
                              hipStream_t stream) {
    const float* y_pre  = (const float*)d_in[0];
    const float* y_true = (const float*)d_in[1];
    const float* x_l    = (const float*)d_in[2];
    const float* wlk    = (const float*)d_in[3];
    double* partial = (double*)d_ws;                       // NBLK*8 bytes
    unsigned* cnt   = (unsigned*)((char*)d_ws + NBLK * 8); // +4 bytes

    hipMemsetAsync(cnt, 0, sizeof(unsigned), stream);
    loss_main<<<NBLK, TPB, 0, stream>>>(y_pre, y_true, x_l, wlk,
                                        partial, cnt, (float*)d_out);
}